// Round 3
// baseline (338.166 us; speedup 1.0000x reference)
//
#include <hip/hip_runtime.h>

// MHA forward. f32 in/out; bf16 MFMA compute, fp32 accum.
// Pipeline: cvt_x + transposeW -> merged QKV GEMM (Q pre-scaled by
//           0.125*log2e) -> transpose_v -> flash attention (32x32x16 MFMA,
//           ZERO LDS / ZERO barriers, K/V from L2, in-register P exchange)
//           -> out GEMM.
// Workspace (u16): WqT,WkT,WvT(contig Bt),WoT (1M ea), xb(8M; ->Vtb),
// Qb, Kb, Vb(8M; ->Ctx) = 72 MB.
//
// R12 vs R11 (attn rewritten):
// (1) 32x32x16 MFMA, swapped operands: S^T tile 32k x 32q per wave; lane
//     (l32,hi) holds S[k=(r&3)+8(r>>2)+4hi][q=l32]. Softmax = 16 in-lane
//     values + one shfl_xor(32).
// (2) NO LDS, NO barriers: K/V per head = 512KB = L2-resident; fragments
//     loaded straight from global; K prefetched 1 tile ahead in regs.
//     Kills R11's barrier/vmcnt(0) drains and the 16cyc/iter P-read bank
//     conflict (LDS gone entirely).
// (3) P -> PV B-fragments fully in-register: 8 cvt_pk + 8 shfl_xor(32)
//     + cndmask (exchange is only across lane+-32 in this layout).
// (4) Perfect balance: wave = heavy+light segment pair w/ qw reversal ->
//     exactly 65 iters/wave; grid 8x64 = 512 blocks = 2/CU all-resident.
// (5) XCD swizzle: 8 bh per XCD -> K/V working set 4MB = one L2.
// (6) Q pre-scaled in gemm_qkv epilogue; defer-max skips O rescale.

typedef unsigned short u16;
typedef __attribute__((ext_vector_type(8))) short short8;   // 8 bf16
typedef __attribute__((ext_vector_type(4))) float floatx4;  // 4 fp32
typedef __attribute__((ext_vector_type(16))) float floatx16;
typedef __attribute__((ext_vector_type(2))) unsigned int uint2v;
typedef __attribute__((ext_vector_type(4))) unsigned int uint4v;

#define NEG_BIG (-1e30f)
#define SCL_LOG2E 0.1803368801111244f  // (1/sqrt(64)) * log2(e)

__device__ __forceinline__ u16 f2bf(float f) {
  unsigned int u = __builtin_bit_cast(unsigned int, f);
  u += 0x7fffu + ((u >> 16) & 1u);
  return (u16)(u >> 16);
}

__device__ __forceinline__ short8 cvt8(const float* __restrict__ p) {
  const floatx4 a = *(const floatx4*)p;
  const floatx4 b = *(const floatx4*)(p + 4);
  short8 r;
  r[0] = (short)f2bf(a[0]); r[1] = (short)f2bf(a[1]);
  r[2] = (short)f2bf(a[2]); r[3] = (short)f2bf(a[3]);
  r[4] = (short)f2bf(b[0]); r[5] = (short)f2bf(b[1]);
  r[6] = (short)f2bf(b[2]); r[7] = (short)f2bf(b[3]);
  return r;
}

// async global->LDS, 16B/lane; LDS dest = wave-uniform base + lane*16 [m97]
__device__ __forceinline__ void gll16(const u16* g, u16* l) {
  __builtin_amdgcn_global_load_lds((const __attribute__((address_space(1))) void*)g,
                                   (__attribute__((address_space(3))) void*)l,
                                   16, 0, 0);
}

// ---------------------------------------------------------------------------
__global__ void cvt_x(const float* __restrict__ x, u16* __restrict__ xb) {
  const int i = blockIdx.x * 256 + threadIdx.x;  // 8 elems each
  *(short8*)(xb + (size_t)i * 8) = cvt8(x + (size_t)i * 8);
}

// ---------------------------------------------------------------------------
// 1024x1024 transpose + f32->bf16 (x4 matrices via grid.z).
__global__ void transpose4(const float* __restrict__ s0, const float* __restrict__ s1,
                           const float* __restrict__ s2, const float* __restrict__ s3,
                           u16* __restrict__ d0, u16* __restrict__ d1,
                           u16* __restrict__ d2, u16* __restrict__ d3) {
  __shared__ u16 tile[64][72];
  const float* src; u16* dst;
  switch (blockIdx.z) {
    case 0: src = s0; dst = d0; break;
    case 1: src = s1; dst = d1; break;
    case 2: src = s2; dst = d2; break;
    default: src = s3; dst = d3; break;
  }
  const int t = threadIdx.x;
  const int c = t & 63, rg = t >> 6;
  const int x0 = blockIdx.x * 64, y0 = blockIdx.y * 64;
#pragma unroll
  for (int i = 0; i < 16; ++i) {
    const int row = rg * 16 + i;
    tile[row][c] = f2bf(src[(size_t)(y0 + row) * 1024 + x0 + c]);
  }
  __syncthreads();
#pragma unroll
  for (int i = 0; i < 16; ++i) {
    const int row = rg * 16 + i;
    dst[(size_t)(x0 + row) * 1024 + y0 + c] = tile[c][row];
  }
}

// ---------------------------------------------------------------------------
// Per-head V transpose: Vb [b,h,l,dh] -> Vt [b,h,dh,l]. Coalesced both sides.
__global__ void transpose_v(const u16* __restrict__ Vb, u16* __restrict__ Vt) {
  __shared__ u16 tile[64][66];  // stride 66: column reads 2-way only
  const int bh = blockIdx.y;
  const int l0 = blockIdx.x * 64;
  const size_t base = (size_t)bh * (2048 * 64);
  const int t = threadIdx.x;
#pragma unroll
  for (int c = t; c < 512; c += 256) {
    const int row = c >> 3, cc = c & 7;
    *(short8*)&tile[row][cc * 8] =
        *(const short8*)(Vb + base + (size_t)(l0 + row) * 64 + cc * 8);
  }
  __syncthreads();
  const int c2 = t & 63, rg = t >> 6;
#pragma unroll
  for (int i = 0; i < 16; ++i) {
    const int dr = rg * 16 + i;
    Vt[base + (size_t)dr * 2048 + l0 + c2] = tile[c2][dr];
  }
}

// ---------------------------------------------------------------------------
// Merged QKV GEMM: A[8192,1024] bf16 @ Bt[3072,1024]^T (WqT|WkT|WvT) + bias.
// 128x128 tile, BK=32, m97 gll staging. All segs write [b,h,l,dh] (coalesced).
// Q segment is pre-scaled by SCL_LOG2E (attn softmax runs in log2 domain).
__global__ __launch_bounds__(256, 2) void gemm_qkv(
    const u16* __restrict__ A, const u16* __restrict__ Bt,
    const float* __restrict__ bq, const float* __restrict__ bk,
    const float* __restrict__ bv,
    u16* __restrict__ Qb, u16* __restrict__ Kb, u16* __restrict__ Vb) {
  const int K = 1024;
  __shared__ __align__(16) u16 As[128 * 32];
  __shared__ __align__(16) u16 Bs[128 * 32];
  const int t = threadIdx.x;
  const int w = t >> 6, l = t & 63;
  const int quad = l >> 4, l16 = l & 15;
  const int m0 = blockIdx.y * 128, n0 = blockIdx.x * 128;
  const int wr = w >> 1, wc = w & 1;

  floatx4 acc[4][4] = {};

  for (int k0 = 0; k0 < K; k0 += 32) {
    __syncthreads();
#pragma unroll
    for (int p = 0; p < 2; ++p) {
      const int c0 = (p * 4 + w) * 64;
      const int c = c0 + l;
      const int row = c >> 2;
      const int koff = (c & 3) * 8;
      gll16(A + (size_t)(m0 + row) * K + k0 + koff, &As[c0 * 8]);
      gll16(Bt + (size_t)(n0 + row) * K + k0 + koff, &Bs[c0 * 8]);
    }
    __syncthreads();

    short8 af[4], bf[4];
#pragma unroll
    for (int i = 0; i < 4; ++i)
      af[i] = *(const short8*)&As[(wr * 64 + i * 16 + l16) * 32 + quad * 8];
#pragma unroll
    for (int j = 0; j < 4; ++j)
      bf[j] = *(const short8*)&Bs[(wc * 64 + j * 16 + l16) * 32 + quad * 8];
#pragma unroll
    for (int i = 0; i < 4; ++i)
#pragma unroll
      for (int j = 0; j < 4; ++j)
        acc[i][j] = __builtin_amdgcn_mfma_f32_16x16x32_bf16(af[i], bf[j], acc[i][j], 0, 0, 0);
  }

  const int seg = n0 >> 10;  // 0=Q 1=K 2=V
  const float* bias = (seg == 0) ? bq : (seg == 1) ? bk : bv;
  u16* dst = (seg == 0) ? Qb : (seg == 1) ? Kb : Vb;
  const float scl = (seg == 0) ? SCL_LOG2E : 1.0f;
#pragma unroll
  for (int j = 0; j < 4; ++j) {
    const int nn = (n0 & 1023) + wc * 64 + j * 16 + l16;
    const float bvs = bias[nn];
    const int h = nn >> 6, dh = nn & 63;
#pragma unroll
    for (int i = 0; i < 4; ++i) {
      const int rb = m0 + wr * 64 + i * 16 + quad * 4;
#pragma unroll
      for (int r = 0; r < 4; ++r) {
        const int m = rb + r;
        const int b = m >> 11, ll = m & 2047;
        dst[((size_t)(b * 16 + h) * 2048 + ll) * 64 + dh] = f2bf((acc[i][j][r] + bvs) * scl);
      }
    }
  }
}

// ---------------------------------------------------------------------------
// Out GEMM: C[M,N] f32 = A[M,K] bf16 @ Bt[N,K]^T + bias[N].
__global__ __launch_bounds__(256, 2) void gemm_out(
    const u16* __restrict__ A, const u16* __restrict__ Bt,
    const float* __restrict__ bias, float* __restrict__ C, int M, int N, int K) {
  __shared__ __align__(16) u16 As[128 * 32];
  __shared__ __align__(16) u16 Bs[128 * 32];
  const int t = threadIdx.x;
  const int w = t >> 6, l = t & 63;
  const int quad = l >> 4, l16 = l & 15;
  const int m0 = blockIdx.y * 128, n0 = blockIdx.x * 128;
  const int wr = w >> 1, wc = w & 1;

  floatx4 acc[4][4] = {};

  for (int k0 = 0; k0 < K; k0 += 32) {
    __syncthreads();
#pragma unroll
    for (int p = 0; p < 2; ++p) {
      const int c0 = (p * 4 + w) * 64;
      const int c = c0 + l;
      const int row = c >> 2;
      const int koff = (c & 3) * 8;
      gll16(A + (size_t)(m0 + row) * K + k0 + koff, &As[c0 * 8]);
      gll16(Bt + (size_t)(n0 + row) * K + k0 + koff, &Bs[c0 * 8]);
    }
    __syncthreads();

    short8 af[4], bf[4];
#pragma unroll
    for (int i = 0; i < 4; ++i)
      af[i] = *(const short8*)&As[(wr * 64 + i * 16 + l16) * 32 + quad * 8];
#pragma unroll
    for (int j = 0; j < 4; ++j)
      bf[j] = *(const short8*)&Bs[(wc * 64 + j * 16 + l16) * 32 + quad * 8];
#pragma unroll
    for (int i = 0; i < 4; ++i)
#pragma unroll
      for (int j = 0; j < 4; ++j)
        acc[i][j] = __builtin_amdgcn_mfma_f32_16x16x32_bf16(af[i], bf[j], acc[i][j], 0, 0, 0);
  }

#pragma unroll
  for (int j = 0; j < 4; ++j) {
    const int n = n0 + wc * 64 + j * 16 + l16;
    const float bvs = bias[n];
#pragma unroll
    for (int i = 0; i < 4; ++i) {
      const int rb = m0 + wr * 64 + i * 16 + quad * 4;
#pragma unroll
      for (int r = 0; r < 4; ++r)
        C[(size_t)(rb + r) * N + n] = acc[i][j][r] + bvs;
    }
  }
}

// ---------------------------------------------------------------------------
// Flash attention, causal, 32x32x16 MFMA, no LDS, no barriers.
// Wave = one 32-q flash worker; block = 4 waves; each wave runs a heavy
// (qblk 15-p) then a light (qblk p) 32-q segment with qw reversed -> exactly
// 65 k-iters (32 keys each) per wave. Grid 8x64 = 512 blocks = 2/CU, all
// co-resident; XCD swizzle puts 8 bh (4MB K+V) on each XCD's L2.
//
// Swapped operands: S^T = mfma(K_frag, Q_frag): lane (l32,hi) holds
// S[k = (r&3)+8*(r>>2)+4*hi][q = l32]. Softmax: 16 in-lane + shfl_xor(32).
// P^T B-fragments built in-register: 8 cvt_pk (k-adjacent reg pairs) +
// 8 shfl_xor(32) + cndmask by hi. PV: O^T = mfma(Vt_frag, P_frag), 2 d-tiles.
__global__ __launch_bounds__(256, 2) void attn_kernel(
    const u16* __restrict__ Q, const u16* __restrict__ K,
    const u16* __restrict__ Vt, u16* __restrict__ ctx) {
  const int t = threadIdx.x;
  const int w = t >> 6, l = t & 63;
  const int l32 = l & 31, hi = l >> 5;

  // XCD swizzle: lin%8 = XCD; give each XCD 8 consecutive bh.
  const int lin = blockIdx.y * 8 + blockIdx.x;  // gridDim.x == 8
  const int xcd = lin & 7, m = lin >> 3;        // m: 0..63
  const int bh = xcd * 8 + (m & 7);
  const int pairp = m >> 3;                     // 0..7
  const size_t base = (size_t)bh * (2048 * 64);
  const int b = bh >> 4, h = bh & 15;

  auto seg = [&](int qblk, int qw) {
    const int qsub = qblk * 128 + qw * 32;  // this wave's 32-q base
    const int nkt = qblk * 4 + qw + 1;      // causal k-tiles of 32
    const int qg = qsub + l32;              // global q row of this lane

    // Q fragments (B-operand): col q=l32, k-dim d = ks*16 + hi*8 + j
    short8 qf[4];
#pragma unroll
    for (int ks = 0; ks < 4; ++ks)
      qf[ks] = *(const short8*)(Q + base + (size_t)qg * 64 + ks * 16 + hi * 8);
    // K fragments for kt=0 (A-operand): row key=l32, k-dim d
    short8 kf[4];
#pragma unroll
    for (int ks = 0; ks < 4; ++ks)
      kf[ks] = *(const short8*)(K + base + (size_t)l32 * 64 + ks * 16 + hi * 8);

    floatx16 o0 = {}, o1 = {};
    float mrun = NEG_BIG, lsum = 0.f;

    auto body = [&](int kt, bool diag) {
      // V fragments for kt, issued early (latency hides under QK + softmax)
      short8 vf[4];  // [dw*2 + k2]: A-operand row d = dw*32+l32, keys k2*16+hi*8
#pragma unroll
      for (int dw = 0; dw < 2; ++dw)
#pragma unroll
        for (int k2 = 0; k2 < 2; ++k2)
          vf[dw * 2 + k2] = *(const short8*)(Vt + base + (size_t)(dw * 32 + l32) * 2048 +
                                             kt * 32 + k2 * 16 + hi * 8);

      // S^T = K Q^T : 4 MFMA 32x32x16
      floatx16 sA = {};
#pragma unroll
      for (int ks = 0; ks < 4; ++ks)
        sA = __builtin_amdgcn_mfma_f32_32x32x16_bf16(kf[ks], qf[ks], sA, 0, 0, 0);

      // prefetch K for kt+1 (main-loop iters always have a next tile)
      if (!diag) {
#pragma unroll
        for (int ks = 0; ks < 4; ++ks)
          kf[ks] = *(const short8*)(K + base + (size_t)((kt + 1) * 32 + l32) * 64 +
                                    ks * 16 + hi * 8);
      }

      // causal mask (diag tile only) + in-lane max (Q pre-scaled to log2 dom)
      float mx = NEG_BIG;
      if (diag) {
#pragma unroll
        for (int r = 0; r < 16; ++r) {
          const int krow = (r & 3) + 8 * (r >> 2) + 4 * hi;
          float v = sA[r];
          if (krow > l32) v = NEG_BIG;
          sA[r] = v;
          mx = fmaxf(mx, v);
        }
      } else {
#pragma unroll
        for (int r = 0; r < 16; ++r) mx = fmaxf(mx, sA[r]);
      }
      mx = fmaxf(mx, __shfl_xor(mx, 32));

      // defer-max: only rescale when the running max actually grows
      if (__any(mx > mrun)) {
        const float mnew = fmaxf(mrun, mx);
        const float al = exp2f(mrun - mnew);
        mrun = mnew;
        lsum *= al;
#pragma unroll
        for (int r = 0; r < 16; ++r) { o0[r] *= al; o1[r] *= al; }
      }

      float rs = 0.f;
#pragma unroll
      for (int r = 0; r < 16; ++r) {
        const float p = exp2f(sA[r] - mrun);
        sA[r] = p;
        rs += p;
      }
      rs += __shfl_xor(rs, 32);
      lsum += rs;

      // P^T B-fragments in-register. w_i = pack(k-pair); partner via lane^32.
      unsigned int wv[8], xv[8];
#pragma unroll
      for (int i = 0; i < 8; ++i)
        asm("v_cvt_pk_bf16_f32 %0, %1, %2"
            : "=v"(wv[i]) : "v"(sA[2 * i]), "v"(sA[2 * i + 1]));
#pragma unroll
      for (int i = 0; i < 8; ++i) xv[i] = __shfl_xor(wv[i], 32);
      // frag0 = keys kt*32 + [0..15]; frag1 = keys kt*32 + [16..31]
      uint4v f0, f1;
      f0[0] = hi ? xv[2] : wv[0];  f0[1] = hi ? xv[3] : wv[1];
      f0[2] = hi ? wv[2] : xv[0];  f0[3] = hi ? wv[3] : xv[1];
      f1[0] = hi ? xv[6] : wv[4];  f1[1] = hi ? xv[7] : wv[5];
      f1[2] = hi ? wv[6] : xv[4];  f1[3] = hi ? wv[7] : xv[5];
      const short8 ap0 = __builtin_bit_cast(short8, f0);
      const short8 ap1 = __builtin_bit_cast(short8, f1);

      // O^T += V^T P^T : 4 MFMA (2 d-tiles x 2 key-halves)
      o0 = __builtin_amdgcn_mfma_f32_32x32x16_bf16(vf[0], ap0, o0, 0, 0, 0);
      o0 = __builtin_amdgcn_mfma_f32_32x32x16_bf16(vf[1], ap1, o0, 0, 0, 0);
      o1 = __builtin_amdgcn_mfma_f32_32x32x16_bf16(vf[2], ap0, o1, 0, 0, 0);
      o1 = __builtin_amdgcn_mfma_f32_32x32x16_bf16(vf[3], ap1, o1, 0, 0, 0);
    };

    for (int kt = 0; kt + 1 < nkt; ++kt) body(kt, false);
    body(nkt - 1, true);

    // normalize + store: lane q = l32; d = dw*32 + (r&3)+8*(r>>2)+4*hi
    const float inv = 1.f / lsum;
    u16* crow = ctx + ((size_t)(b * 2048 + qg)) * 1024 + h * 64;
#pragma unroll
    for (int dw = 0; dw < 2; ++dw) {
#pragma unroll
      for (int run = 0; run < 4; ++run) {
        const float a0 = (dw ? o1[run * 4 + 0] : o0[run * 4 + 0]) * inv;
        const float a1 = (dw ? o1[run * 4 + 1] : o0[run * 4 + 1]) * inv;
        const float a2 = (dw ? o1[run * 4 + 2] : o0[run * 4 + 2]) * inv;
        const float a3 = (dw ? o1[run * 4 + 3] : o0[run * 4 + 3]) * inv;
        unsigned int lo, hw;
        asm("v_cvt_pk_bf16_f32 %0, %1, %2" : "=v"(lo) : "v"(a0), "v"(a1));
        asm("v_cvt_pk_bf16_f32 %0, %1, %2" : "=v"(hw) : "v"(a2), "v"(a3));
        uint2v pk; pk.x = lo; pk.y = hw;
        *(uint2v*)(crow + dw * 32 + run * 8 + hi * 4) = pk;
      }
    }
  };

  // heavy then light segment; qw reversed in light -> 65 iters for EVERY wave
  seg(15 - pairp, w);
  seg(pairp, 3 - w);
}

// ---------------------------------------------------------------------------
extern "C" void kernel_launch(void* const* d_in, const int* in_sizes, int n_in,
                              void* d_out, int out_size, void* d_ws, size_t ws_size,
                              hipStream_t stream) {
  const float* x  = (const float*)d_in[0];
  // d_in[1] = attn_mask (causal tril) — implemented analytically
  const float* Wq = (const float*)d_in[2];
  const float* bq = (const float*)d_in[3];
  const float* Wk = (const float*)d_in[4];
  const float* bk = (const float*)d_in[5];
  const float* Wv = (const float*)d_in[6];
  const float* bv = (const float*)d_in[7];
  const float* Wo = (const float*)d_in[8];
  const float* bo = (const float*)d_in[9];

  u16* ws = (u16*)d_ws;
  const size_t WSZ = 1u << 20;   // 1024*1024
  const size_t TSZ = 8u << 20;   // 8192*1024
  u16* WqT = ws;                 // WqT|WkT|WvT contiguous = 3072x1024 Bt
  u16* WkT = ws + WSZ;
  u16* WvT = ws + 2 * WSZ;
  u16* WoT = ws + 3 * WSZ;
  u16* xb  = ws + 4 * WSZ;       // x bf16; dead after gemm_qkv -> reused as Vtb
  u16* Qb  = xb + TSZ;
  u16* Kb  = Qb + TSZ;
  u16* Vb  = Kb + TSZ;           // V [b,h,l,dh]; dead after transpose_v -> Ctx
  u16* Vtb = xb;
  u16* Ctx = Vb;

  const dim3 tb(256);
  cvt_x<<<dim3(4096), tb, 0, stream>>>(x, xb);
  transpose4<<<dim3(16, 16, 4), tb, 0, stream>>>(Wq, Wk, Wv, Wo, WqT, WkT, WvT, WoT);
  gemm_qkv<<<dim3(24, 64), tb, 0, stream>>>(xb, WqT, bq, bk, bv, Qb, Kb, Vb);
  transpose_v<<<dim3(32, 64), tb, 0, stream>>>(Vb, Vtb);
  attn_kernel<<<dim3(8, 64), tb, 0, stream>>>(Qb, Kb, Vtb, Ctx);
  gemm_out<<<dim3(8, 64), tb, 0, stream>>>(Ctx, WoT, bo, (float*)d_out, 8192, 1024, 1024);
}

// Round 5
// 292.330 us; speedup vs baseline: 1.1568x; 1.1568x over previous
//
#include <hip/hip_runtime.h>

// MHA forward. f32 in/out; bf16 MFMA compute (16x16x32), fp32 accum.
// Pipeline: cvt_x + transposeW -> merged QKV GEMM (Q pre-scaled by
//           0.125*log2e) -> transpose_v -> flash attention (8-wave blocks,
//           q-tile 128, dbuf gll16 64x64 K/V tiles, LDS P-hop, paired
//           q-tiles, XCD remap) -> out GEMM.
// Workspace (u16): WqT,WkT,WvT(contig Bt),WoT (1M ea), xb(8M; ->Vtb),
// Qb, Kb, Vb(8M; ->Ctx) = 72 MB.
//
// R14 = R11's proven per-wave body (97us, passed) in an 8-wave chassis:
// (1) 512-thread blocks, q-tile 128 sharing each 64x64 K/V tile -> staging
//     traffic and barriers per q-row halve. LDS 48KB -> 2 blocks/CU =
//     16 waves/CU (R11: 3 blocks x 4 waves = 12).
// (2) Perfect balance kept: block = q-tile pair (15-pp, pp) -> 34 iters each;
//     grid 8x64 = 512 = exactly 2/CU.
// (3) XCD remap (R12-proven): 8 bh per XCD -> K/V L2-resident per XCD.
// (4) Q pre-scaled in gemm_qkv; exp2-domain softmax; defer-max THR=8;
//     s_setprio around MFMA clusters.
// (5) R13's in-register P-exchange REVERTED (register selection provably
//     needs dest-side qh; shfl gives source-side). LDS P-hop verbatim R11.

typedef unsigned short u16;
typedef __attribute__((ext_vector_type(8))) short short8;   // 8 bf16
typedef __attribute__((ext_vector_type(4))) float floatx4;  // 4 fp32
typedef __attribute__((ext_vector_type(2))) unsigned int uint2v;

#define NEG_BIG (-1e30f)
#define SCL_LOG2E 0.1803368801111244f  // (1/sqrt(64)) * log2(e)

__device__ __forceinline__ u16 f2bf(float f) {
  unsigned int u = __builtin_bit_cast(unsigned int, f);
  u += 0x7fffu + ((u >> 16) & 1u);
  return (u16)(u >> 16);
}

__device__ __forceinline__ short8 cvt8(const float* __restrict__ p) {
  const floatx4 a = *(const floatx4*)p;
  const floatx4 b = *(const floatx4*)(p + 4);
  short8 r;
  r[0] = (short)f2bf(a[0]); r[1] = (short)f2bf(a[1]);
  r[2] = (short)f2bf(a[2]); r[3] = (short)f2bf(a[3]);
  r[4] = (short)f2bf(b[0]); r[5] = (short)f2bf(b[1]);
  r[6] = (short)f2bf(b[2]); r[7] = (short)f2bf(b[3]);
  return r;
}

// async global->LDS, 16B/lane; LDS dest = wave-uniform base + lane*16 [m97]
__device__ __forceinline__ void gll16(const u16* g, u16* l) {
  __builtin_amdgcn_global_load_lds((const __attribute__((address_space(1))) void*)g,
                                   (__attribute__((address_space(3))) void*)l,
                                   16, 0, 0);
}

// ---------------------------------------------------------------------------
__global__ void cvt_x(const float* __restrict__ x, u16* __restrict__ xb) {
  const int i = blockIdx.x * 256 + threadIdx.x;  // 8 elems each
  *(short8*)(xb + (size_t)i * 8) = cvt8(x + (size_t)i * 8);
}

// ---------------------------------------------------------------------------
// 1024x1024 transpose + f32->bf16 (x4 matrices via grid.z).
__global__ void transpose4(const float* __restrict__ s0, const float* __restrict__ s1,
                           const float* __restrict__ s2, const float* __restrict__ s3,
                           u16* __restrict__ d0, u16* __restrict__ d1,
                           u16* __restrict__ d2, u16* __restrict__ d3) {
  __shared__ u16 tile[64][72];
  const float* src; u16* dst;
  switch (blockIdx.z) {
    case 0: src = s0; dst = d0; break;
    case 1: src = s1; dst = d1; break;
    case 2: src = s2; dst = d2; break;
    default: src = s3; dst = d3; break;
  }
  const int t = threadIdx.x;
  const int c = t & 63, rg = t >> 6;
  const int x0 = blockIdx.x * 64, y0 = blockIdx.y * 64;
#pragma unroll
  for (int i = 0; i < 16; ++i) {
    const int row = rg * 16 + i;
    tile[row][c] = f2bf(src[(size_t)(y0 + row) * 1024 + x0 + c]);
  }
  __syncthreads();
#pragma unroll
  for (int i = 0; i < 16; ++i) {
    const int row = rg * 16 + i;
    dst[(size_t)(x0 + row) * 1024 + y0 + c] = tile[c][row];
  }
}

// ---------------------------------------------------------------------------
// Per-head V transpose: Vb [b,h,l,dh] -> Vt [b,h,dh,l]. Coalesced both sides.
__global__ void transpose_v(const u16* __restrict__ Vb, u16* __restrict__ Vt) {
  __shared__ u16 tile[64][66];  // stride 66: column reads 2-way only
  const int bh = blockIdx.y;
  const int l0 = blockIdx.x * 64;
  const size_t base = (size_t)bh * (2048 * 64);
  const int t = threadIdx.x;
#pragma unroll
  for (int c = t; c < 512; c += 256) {
    const int row = c >> 3, cc = c & 7;
    *(short8*)&tile[row][cc * 8] =
        *(const short8*)(Vb + base + (size_t)(l0 + row) * 64 + cc * 8);
  }
  __syncthreads();
  const int c2 = t & 63, rg = t >> 6;
#pragma unroll
  for (int i = 0; i < 16; ++i) {
    const int dr = rg * 16 + i;
    Vt[base + (size_t)dr * 2048 + l0 + c2] = tile[c2][dr];
  }
}

// ---------------------------------------------------------------------------
// Merged QKV GEMM: A[8192,1024] bf16 @ Bt[3072,1024]^T (WqT|WkT|WvT) + bias.
// 128x128 tile, BK=32, m97 gll staging. All segs write [b,h,l,dh] (coalesced).
// Q segment is pre-scaled by SCL_LOG2E (attn softmax runs in log2 domain).
__global__ __launch_bounds__(256, 2) void gemm_qkv(
    const u16* __restrict__ A, const u16* __restrict__ Bt,
    const float* __restrict__ bq, const float* __restrict__ bk,
    const float* __restrict__ bv,
    u16* __restrict__ Qb, u16* __restrict__ Kb, u16* __restrict__ Vb) {
  const int K = 1024;
  __shared__ __align__(16) u16 As[128 * 32];
  __shared__ __align__(16) u16 Bs[128 * 32];
  const int t = threadIdx.x;
  const int w = t >> 6, l = t & 63;
  const int quad = l >> 4, l16 = l & 15;
  const int m0 = blockIdx.y * 128, n0 = blockIdx.x * 128;
  const int wr = w >> 1, wc = w & 1;

  floatx4 acc[4][4] = {};

  for (int k0 = 0; k0 < K; k0 += 32) {
    __syncthreads();
#pragma unroll
    for (int p = 0; p < 2; ++p) {
      const int c0 = (p * 4 + w) * 64;
      const int c = c0 + l;
      const int row = c >> 2;
      const int koff = (c & 3) * 8;
      gll16(A + (size_t)(m0 + row) * K + k0 + koff, &As[c0 * 8]);
      gll16(Bt + (size_t)(n0 + row) * K + k0 + koff, &Bs[c0 * 8]);
    }
    __syncthreads();

    short8 af[4], bf[4];
#pragma unroll
    for (int i = 0; i < 4; ++i)
      af[i] = *(const short8*)&As[(wr * 64 + i * 16 + l16) * 32 + quad * 8];
#pragma unroll
    for (int j = 0; j < 4; ++j)
      bf[j] = *(const short8*)&Bs[(wc * 64 + j * 16 + l16) * 32 + quad * 8];
#pragma unroll
    for (int i = 0; i < 4; ++i)
#pragma unroll
      for (int j = 0; j < 4; ++j)
        acc[i][j] = __builtin_amdgcn_mfma_f32_16x16x32_bf16(af[i], bf[j], acc[i][j], 0, 0, 0);
  }

  const int seg = n0 >> 10;  // 0=Q 1=K 2=V
  const float* bias = (seg == 0) ? bq : (seg == 1) ? bk : bv;
  u16* dst = (seg == 0) ? Qb : (seg == 1) ? Kb : Vb;
  const float scl = (seg == 0) ? SCL_LOG2E : 1.0f;
#pragma unroll
  for (int j = 0; j < 4; ++j) {
    const int nn = (n0 & 1023) + wc * 64 + j * 16 + l16;
    const float bvs = bias[nn];
    const int h = nn >> 6, dh = nn & 63;
#pragma unroll
    for (int i = 0; i < 4; ++i) {
      const int rb = m0 + wr * 64 + i * 16 + quad * 4;
#pragma unroll
      for (int r = 0; r < 4; ++r) {
        const int m = rb + r;
        const int b = m >> 11, ll = m & 2047;
        dst[((size_t)(b * 16 + h) * 2048 + ll) * 64 + dh] = f2bf((acc[i][j][r] + bvs) * scl);
      }
    }
  }
}

// ---------------------------------------------------------------------------
// Out GEMM: C[M,N] f32 = A[M,K] bf16 @ Bt[N,K]^T + bias[N].
__global__ __launch_bounds__(256, 2) void gemm_out(
    const u16* __restrict__ A, const u16* __restrict__ Bt,
    const float* __restrict__ bias, float* __restrict__ C, int M, int N, int K) {
  __shared__ __align__(16) u16 As[128 * 32];
  __shared__ __align__(16) u16 Bs[128 * 32];
  const int t = threadIdx.x;
  const int w = t >> 6, l = t & 63;
  const int quad = l >> 4, l16 = l & 15;
  const int m0 = blockIdx.y * 128, n0 = blockIdx.x * 128;
  const int wr = w >> 1, wc = w & 1;

  floatx4 acc[4][4] = {};

  for (int k0 = 0; k0 < K; k0 += 32) {
    __syncthreads();
#pragma unroll
    for (int p = 0; p < 2; ++p) {
      const int c0 = (p * 4 + w) * 64;
      const int c = c0 + l;
      const int row = c >> 2;
      const int koff = (c & 3) * 8;
      gll16(A + (size_t)(m0 + row) * K + k0 + koff, &As[c0 * 8]);
      gll16(Bt + (size_t)(n0 + row) * K + k0 + koff, &Bs[c0 * 8]);
    }
    __syncthreads();

    short8 af[4], bf[4];
#pragma unroll
    for (int i = 0; i < 4; ++i)
      af[i] = *(const short8*)&As[(wr * 64 + i * 16 + l16) * 32 + quad * 8];
#pragma unroll
    for (int j = 0; j < 4; ++j)
      bf[j] = *(const short8*)&Bs[(wc * 64 + j * 16 + l16) * 32 + quad * 8];
#pragma unroll
    for (int i = 0; i < 4; ++i)
#pragma unroll
      for (int j = 0; j < 4; ++j)
        acc[i][j] = __builtin_amdgcn_mfma_f32_16x16x32_bf16(af[i], bf[j], acc[i][j], 0, 0, 0);
  }

#pragma unroll
  for (int j = 0; j < 4; ++j) {
    const int n = n0 + wc * 64 + j * 16 + l16;
    const float bvs = bias[n];
#pragma unroll
    for (int i = 0; i < 4; ++i) {
      const int rb = m0 + wr * 64 + i * 16 + quad * 4;
#pragma unroll
      for (int r = 0; r < 4; ++r)
        C[(size_t)(rb + r) * N + n] = acc[i][j][r] + bvs;
    }
  }
}

// ---------------------------------------------------------------------------
// Flash attention, causal. 512-thread blocks (8 waves x 16 q-rows = q-tile
// 128) sharing 64x64 K/V tiles double-buffered via gll16 with chunk-XOR
// swizzle. Block = q-tile pair (15-pp, pp) -> exactly 34 k-iters per block;
// grid 8x64 = 512 blocks = 2/CU (LDS 48KB). XCD remap: 8 bh per XCD L2.
// ONE __syncthreads per k-tile.
//
// Per-wave body = R11's proven kernel: swapped-operand MFMA
// s = mfma(K_frag, Q_frag) -> S^T: lane(quad,l16) holds
// S[k = kt*64 + tn*16+quad*4+r][q = l16]. Softmax in-lane + shfl_xor(16/32),
// exp2 domain (Q pre-scaled), defer-max THR=8. P -> bf16 pairs via
// v_cvt_pk_bf16_f32 -> wave-private swizzled LDS (4x ds_write_b64) ->
// 2x ds_read_b128 -> PV mfma(Vt_frag, P_frag).
// Waves fully below the diagonal skip compute (staging+barrier only);
// per-lane causal compare only on (up to 2) diagonal-crossing tiles.
__global__ __launch_bounds__(512, 4) void attn_kernel(
    const u16* __restrict__ Q, const u16* __restrict__ K,
    const u16* __restrict__ Vt, u16* __restrict__ ctx) {
  __shared__ __align__(16) u16 Ks[2][64 * 64];
  __shared__ __align__(16) u16 Vs[2][64 * 64];
  __shared__ __align__(16) u16 Ps[8 * 16 * 64];

  const int t = threadIdx.x;
  const int w = t >> 6, l = t & 63;
  const int quad = l >> 4, l16 = l & 15;
  // XCD remap: consecutive HW block ids round-robin XCDs; each XCD gets 8
  // consecutive bh (4MB K+V = one L2) across all pair indices.
  const int lin = blockIdx.y * 8 + blockIdx.x;  // gridDim.x == 8
  const int bh = (lin & 7) * 8 + ((lin >> 3) & 7);
  const int pp = lin >> 6;  // 0..7
  const size_t base = (size_t)bh * (2048 * 64);
  const int b = bh >> 4, h = bh & 15;
  u16* Pw = &Ps[w * 16 * 64];
  unsigned int* Pw32 = (unsigned int*)Pw;

  // staging geometry: phys chunk pc = w*64 + l; logical row sr = pc>>3,
  // chunk sc = (pc&7) ^ (sr&7). gll16 dest = chunk-contiguous (lane*16).
  const int pc = w * 64 + l;
  const int sr = pc >> 3, sc = (pc & 7) ^ (sr & 7);
  const int swz = (l16 & 7);  // fragment-read chunk swizzle

  auto run_seg = [&](int p) {
    const int q0 = p * 128;
    const int nkt = 2 * p + 2;           // causal k-tiles of 64
    const int qg = q0 + w * 16 + l16;    // this lane's q row
    const int qmax = q0 + w * 16 + 15;   // wave's max q
    const int qmin = q0 + w * 16;        // wave's min q

    // Q fragments (lane's l16 = q-row): k = ks*32+quad*8
    short8 aq[2];
#pragma unroll
    for (int ks = 0; ks < 2; ++ks)
      aq[ks] = *(const short8*)(Q + base + (size_t)qg * 64 + ks * 32 + quad * 8);

    // prefetch tile 0 into buf 0 (1 K-chunk + 1 V-chunk per wave)
    gll16(K + base + (size_t)sr * 64 + sc * 8, &Ks[0][(w * 64) * 8]);
    gll16(Vt + base + (size_t)sr * 2048 + sc * 8, &Vs[0][(w * 64) * 8]);

    floatx4 o[4] = {};
    float mrun = NEG_BIG, lsum = 0.f;

    for (int kt = 0; kt < nkt; ++kt) {
      const int cur = kt & 1, nxt = cur ^ 1;
      __syncthreads();  // drains gll16s for buf[cur]; protects buf[nxt]
      if (kt + 1 < nkt) {
        const int kn = (kt + 1) * 64;
        gll16(K + base + (size_t)(kn + sr) * 64 + sc * 8, &Ks[nxt][(w * 64) * 8]);
        gll16(Vt + base + (size_t)sr * 2048 + kn + sc * 8, &Vs[nxt][(w * 64) * 8]);
      }
      const int kbase = kt * 64;
      if (kbase > qmax) continue;  // fully-masked wave: barrier+staging only
      const bool masked = (kbase + 63 > qmin);  // wave-uniform

      // S^T = K Q^T : 8 MFMA (swapped operands); K frag row tn*16+l16
      floatx4 s[4] = {};
      __builtin_amdgcn_s_setprio(1);
#pragma unroll
      for (int ks = 0; ks < 2; ++ks)
#pragma unroll
        for (int tn = 0; tn < 4; ++tn) {
          const short8 bk = *(const short8*)&Ks[cur][(tn * 16 + l16) * 64 + (((ks * 4 + quad) ^ swz) << 3)];
          s[tn] = __builtin_amdgcn_mfma_f32_16x16x32_bf16(bk, aq[ks], s[tn], 0, 0, 0);
        }
      __builtin_amdgcn_s_setprio(0);

      // causal mask (diag-crossing tiles only) + in-lane max (log2 domain).
      float mx = NEG_BIG;
      if (masked) {
#pragma unroll
        for (int tn = 0; tn < 4; ++tn)
#pragma unroll
          for (int r = 0; r < 4; ++r) {
            float v = s[tn][r];
            if (kbase + tn * 16 + quad * 4 + r > qg) v = NEG_BIG;
            s[tn][r] = v;
            mx = fmaxf(mx, v);
          }
      } else {
#pragma unroll
        for (int tn = 0; tn < 4; ++tn)
#pragma unroll
          for (int r = 0; r < 4; ++r) mx = fmaxf(mx, s[tn][r]);
      }
      // cross-quad (same q lives in lanes l16, l16+16, l16+32, l16+48)
      mx = fmaxf(mx, __shfl_xor(mx, 16));
      mx = fmaxf(mx, __shfl_xor(mx, 32));

      // defer-max: rescale only when the max grows by more than THR=8.
      if (!__all(mx - mrun <= 8.f)) {
        const float mnew = fmaxf(mrun, mx);
        const float al = exp2f(mrun - mnew);
        mrun = mnew;
        lsum *= al;
#pragma unroll
        for (int td = 0; td < 4; ++td)
#pragma unroll
          for (int r = 0; r < 4; ++r) o[td][r] *= al;
      }

      float rs = 0.f;
#pragma unroll
      for (int tn = 0; tn < 4; ++tn)
#pragma unroll
        for (int r = 0; r < 4; ++r) {
          const float pv = exp2f(s[tn][r] - mrun);
          s[tn][r] = pv;
          rs += pv;
        }

      // P: pack k-pairs -> 2x u32 per tn, one ds_write_b64 each.
      // u32 word k2 = 8*tn + 2*quad + p; chunk c = 2*tn + (quad>>1);
      // swizzled chunk cc = c ^ swz; intra-chunk offset 2*(quad&1)+p.
#pragma unroll
      for (int tn = 0; tn < 4; ++tn) {
        unsigned int p0, p1;
        asm("v_cvt_pk_bf16_f32 %0, %1, %2"
            : "=v"(p0) : "v"(s[tn][0]), "v"(s[tn][1]));
        asm("v_cvt_pk_bf16_f32 %0, %1, %2"
            : "=v"(p1) : "v"(s[tn][2]), "v"(s[tn][3]));
        const int cc = (2 * tn + (quad >> 1)) ^ swz;
        uint2v pr; pr.x = p0; pr.y = p1;
        *(uint2v*)&Pw32[l16 * 32 + cc * 4 + 2 * (quad & 1)] = pr;
      }
      rs += __shfl_xor(rs, 16);
      rs += __shfl_xor(rs, 32);
      lsum += rs;
      __asm__ volatile("s_waitcnt lgkmcnt(0)" ::: "memory");
      __builtin_amdgcn_wave_barrier();

      // P fragment (B-operand): row l16 = q, k = ks*32+quad*8..+7 (de-swz)
      short8 ap[2];
#pragma unroll
      for (int ks = 0; ks < 2; ++ks)
        ap[ks] = *(const short8*)&Pw[l16 * 64 + (((ks * 4 + quad) ^ swz) << 3)];

      // O^T += V^T P^T : 8 MFMA (swapped); Vt frag row td*16+l16 (=dh)
      __builtin_amdgcn_s_setprio(1);
#pragma unroll
      for (int ks = 0; ks < 2; ++ks)
#pragma unroll
        for (int td = 0; td < 4; ++td) {
          const short8 bv = *(const short8*)&Vs[cur][(td * 16 + l16) * 64 + (((ks * 4 + quad) ^ swz) << 3)];
          o[td] = __builtin_amdgcn_mfma_f32_16x16x32_bf16(bv, ap[ks], o[td], 0, 0, 0);
        }
      __builtin_amdgcn_s_setprio(0);
    }

    // normalize + store ctx[b, qg, h*64 + d]; lane q = l16, d = td*16+quad*4+r
    const float inv = 1.f / lsum;
    u16* crow = ctx + ((size_t)(b * 2048 + qg)) * 1024 + h * 64;
#pragma unroll
    for (int td = 0; td < 4; ++td) {
      unsigned int lo, hi;
      asm("v_cvt_pk_bf16_f32 %0, %1, %2"
          : "=v"(lo) : "v"(o[td][0] * inv), "v"(o[td][1] * inv));
      asm("v_cvt_pk_bf16_f32 %0, %1, %2"
          : "=v"(hi) : "v"(o[td][2] * inv), "v"(o[td][3] * inv));
      uint2v pk;
      pk.x = lo; pk.y = hi;
      *(uint2v*)(crow + td * 16 + quad * 4) = pk;
    }
  };

  run_seg(15 - pp);   // heavy segment: nkt in [18,32]
  __syncthreads();    // protect buffers before re-prefetch
  run_seg(pp);        // light segment: nkt in [2,16]
}

// ---------------------------------------------------------------------------
extern "C" void kernel_launch(void* const* d_in, const int* in_sizes, int n_in,
                              void* d_out, int out_size, void* d_ws, size_t ws_size,
                              hipStream_t stream) {
  const float* x  = (const float*)d_in[0];
  // d_in[1] = attn_mask (causal tril) — implemented analytically
  const float* Wq = (const float*)d_in[2];
  const float* bq = (const float*)d_in[3];
  const float* Wk = (const float*)d_in[4];
  const float* bk = (const float*)d_in[5];
  const float* Wv = (const float*)d_in[6];
  const float* bv = (const float*)d_in[7];
  const float* Wo = (const float*)d_in[8];
  const float* bo = (const float*)d_in[9];

  u16* ws = (u16*)d_ws;
  const size_t WSZ = 1u << 20;   // 1024*1024
  const size_t TSZ = 8u << 20;   // 8192*1024
  u16* WqT = ws;                 // WqT|WkT|WvT contiguous = 3072x1024 Bt
  u16* WkT = ws + WSZ;
  u16* WvT = ws + 2 * WSZ;
  u16* WoT = ws + 3 * WSZ;
  u16* xb  = ws + 4 * WSZ;       // x bf16; dead after gemm_qkv -> reused as Vtb
  u16* Qb  = xb + TSZ;
  u16* Kb  = Qb + TSZ;
  u16* Vb  = Kb + TSZ;           // V [b,h,l,dh]; dead after transpose_v -> Ctx
  u16* Vtb = xb;
  u16* Ctx = Vb;

  const dim3 tb(256);
  cvt_x<<<dim3(4096), tb, 0, stream>>>(x, xb);
  transpose4<<<dim3(16, 16, 4), tb, 0, stream>>>(Wq, Wk, Wv, Wo, WqT, WkT, WvT, WoT);
  gemm_qkv<<<dim3(24, 64), tb, 0, stream>>>(xb, WqT, bq, bk, bv, Qb, Kb, Vb);
  transpose_v<<<dim3(32, 64), tb, 0, stream>>>(Vb, Vtb);
  attn_kernel<<<dim3(8, 64), dim3(512), 0, stream>>>(Qb, Kb, Vtb, Ctx);
  gemm_out<<<dim3(8, 64), tb, 0, stream>>>(Ctx, WoT, bo, (float*)d_out, 8192, 1024, 1024);
}

// Round 6
// 285.800 us; speedup vs baseline: 1.1832x; 1.0228x over previous
//
#include <hip/hip_runtime.h>

// MHA forward. f32 in/out; bf16 MFMA compute (16x16x32), fp32 accum.
// Pipeline: cvt_x + transposeW -> merged QKV GEMM (Q pre-scaled by
//           0.125*log2e, XCD-swizzled) -> transpose_v -> flash attention
//           (8-wave blocks, q-tile 128, dbuf gll16 64x64 K/V tiles, LDS
//           P-hop, paired q-tiles, XCD remap, MFMA-lsum) -> out GEMM
//           (XCD-swizzled).
// Workspace (u16): WqT,WkT,WvT(contig Bt),WoT (1M ea), xb(8M; ->Vtb),
// Qb, Kb, Vb(8M; ->Ctx) = 72 MB.
//
// R15 vs R14:
// (1) attn lsum via MFMA ones-column: lacc = mfma(ones, ap[ks], lacc) gives
//     every lane the full 64-key column sum (C[i][q] = sum_k P[k][q], all i
//     equal) -> removes 16 v_add + 2 shfl + 1 add per iter from the VALU
//     critical path (kernel is VALU-issue-bound: 60% VALUBusy vs 17% Mfma).
// (2) in-lane 16-value max via v_max3 tree (8 instrs vs 15).
// (3) XCD-aware chunked swizzle on gemm_qkv (1536 blocks -> 192/XCD = 8
//     m-panels) and gemm_out (512 -> 64/XCD): A-panel reuse in local L2.

typedef unsigned short u16;
typedef __attribute__((ext_vector_type(8))) short short8;   // 8 bf16
typedef __attribute__((ext_vector_type(4))) float floatx4;  // 4 fp32
typedef __attribute__((ext_vector_type(2))) unsigned int uint2v;

#define NEG_BIG (-1e30f)
#define SCL_LOG2E 0.1803368801111244f  // (1/sqrt(64)) * log2(e)

__device__ __forceinline__ u16 f2bf(float f) {
  unsigned int u = __builtin_bit_cast(unsigned int, f);
  u += 0x7fffu + ((u >> 16) & 1u);
  return (u16)(u >> 16);
}

__device__ __forceinline__ float max3f(float a, float b, float c) {
  float d;
  asm("v_max3_f32 %0, %1, %2, %3" : "=v"(d) : "v"(a), "v"(b), "v"(c));
  return d;
}

__device__ __forceinline__ short8 cvt8(const float* __restrict__ p) {
  const floatx4 a = *(const floatx4*)p;
  const floatx4 b = *(const floatx4*)(p + 4);
  short8 r;
  r[0] = (short)f2bf(a[0]); r[1] = (short)f2bf(a[1]);
  r[2] = (short)f2bf(a[2]); r[3] = (short)f2bf(a[3]);
  r[4] = (short)f2bf(b[0]); r[5] = (short)f2bf(b[1]);
  r[6] = (short)f2bf(b[2]); r[7] = (short)f2bf(b[3]);
  return r;
}

// async global->LDS, 16B/lane; LDS dest = wave-uniform base + lane*16 [m97]
__device__ __forceinline__ void gll16(const u16* g, u16* l) {
  __builtin_amdgcn_global_load_lds((const __attribute__((address_space(1))) void*)g,
                                   (__attribute__((address_space(3))) void*)l,
                                   16, 0, 0);
}

// ---------------------------------------------------------------------------
__global__ void cvt_x(const float* __restrict__ x, u16* __restrict__ xb) {
  const int i = blockIdx.x * 256 + threadIdx.x;  // 8 elems each
  *(short8*)(xb + (size_t)i * 8) = cvt8(x + (size_t)i * 8);
}

// ---------------------------------------------------------------------------
// 1024x1024 transpose + f32->bf16 (x4 matrices via grid.z).
__global__ void transpose4(const float* __restrict__ s0, const float* __restrict__ s1,
                           const float* __restrict__ s2, const float* __restrict__ s3,
                           u16* __restrict__ d0, u16* __restrict__ d1,
                           u16* __restrict__ d2, u16* __restrict__ d3) {
  __shared__ u16 tile[64][72];
  const float* src; u16* dst;
  switch (blockIdx.z) {
    case 0: src = s0; dst = d0; break;
    case 1: src = s1; dst = d1; break;
    case 2: src = s2; dst = d2; break;
    default: src = s3; dst = d3; break;
  }
  const int t = threadIdx.x;
  const int c = t & 63, rg = t >> 6;
  const int x0 = blockIdx.x * 64, y0 = blockIdx.y * 64;
#pragma unroll
  for (int i = 0; i < 16; ++i) {
    const int row = rg * 16 + i;
    tile[row][c] = f2bf(src[(size_t)(y0 + row) * 1024 + x0 + c]);
  }
  __syncthreads();
#pragma unroll
  for (int i = 0; i < 16; ++i) {
    const int row = rg * 16 + i;
    dst[(size_t)(x0 + row) * 1024 + y0 + c] = tile[c][row];
  }
}

// ---------------------------------------------------------------------------
// Per-head V transpose: Vb [b,h,l,dh] -> Vt [b,h,dh,l]. Coalesced both sides.
__global__ void transpose_v(const u16* __restrict__ Vb, u16* __restrict__ Vt) {
  __shared__ u16 tile[64][66];  // stride 66: column reads 2-way only
  const int bh = blockIdx.y;
  const int l0 = blockIdx.x * 64;
  const size_t base = (size_t)bh * (2048 * 64);
  const int t = threadIdx.x;
#pragma unroll
  for (int c = t; c < 512; c += 256) {
    const int row = c >> 3, cc = c & 7;
    *(short8*)&tile[row][cc * 8] =
        *(const short8*)(Vb + base + (size_t)(l0 + row) * 64 + cc * 8);
  }
  __syncthreads();
  const int c2 = t & 63, rg = t >> 6;
#pragma unroll
  for (int i = 0; i < 16; ++i) {
    const int dr = rg * 16 + i;
    Vt[base + (size_t)dr * 2048 + l0 + c2] = tile[c2][dr];
  }
}

// ---------------------------------------------------------------------------
// Merged QKV GEMM: A[8192,1024] bf16 @ Bt[3072,1024]^T (WqT|WkT|WvT) + bias.
// 128x128 tile, BK=32, m97 gll staging. All segs write [b,h,l,dh] (coalesced).
// Q segment is pre-scaled by SCL_LOG2E (attn softmax runs in log2 domain).
// XCD-chunked block swizzle: 192 blocks (8 m-panels x 24) per XCD.
__global__ __launch_bounds__(256, 2) void gemm_qkv(
    const u16* __restrict__ A, const u16* __restrict__ Bt,
    const float* __restrict__ bq, const float* __restrict__ bk,
    const float* __restrict__ bv,
    u16* __restrict__ Qb, u16* __restrict__ Kb, u16* __restrict__ Vb) {
  const int K = 1024;
  __shared__ __align__(16) u16 As[128 * 32];
  __shared__ __align__(16) u16 Bs[128 * 32];
  const int t = threadIdx.x;
  const int w = t >> 6, l = t & 63;
  const int quad = l >> 4, l16 = l & 15;
  const int lin = blockIdx.y * 24 + blockIdx.x;       // 0..1535
  const int nl = (lin & 7) * 192 + (lin >> 3);        // XCD-chunked remap
  const int m0 = (nl / 24) * 128, n0 = (nl % 24) * 128;
  const int wr = w >> 1, wc = w & 1;

  floatx4 acc[4][4] = {};

  for (int k0 = 0; k0 < K; k0 += 32) {
    __syncthreads();
#pragma unroll
    for (int p = 0; p < 2; ++p) {
      const int c0 = (p * 4 + w) * 64;
      const int c = c0 + l;
      const int row = c >> 2;
      const int koff = (c & 3) * 8;
      gll16(A + (size_t)(m0 + row) * K + k0 + koff, &As[c0 * 8]);
      gll16(Bt + (size_t)(n0 + row) * K + k0 + koff, &Bs[c0 * 8]);
    }
    __syncthreads();

    short8 af[4], bf[4];
#pragma unroll
    for (int i = 0; i < 4; ++i)
      af[i] = *(const short8*)&As[(wr * 64 + i * 16 + l16) * 32 + quad * 8];
#pragma unroll
    for (int j = 0; j < 4; ++j)
      bf[j] = *(const short8*)&Bs[(wc * 64 + j * 16 + l16) * 32 + quad * 8];
#pragma unroll
    for (int i = 0; i < 4; ++i)
#pragma unroll
      for (int j = 0; j < 4; ++j)
        acc[i][j] = __builtin_amdgcn_mfma_f32_16x16x32_bf16(af[i], bf[j], acc[i][j], 0, 0, 0);
  }

  const int seg = n0 >> 10;  // 0=Q 1=K 2=V
  const float* bias = (seg == 0) ? bq : (seg == 1) ? bk : bv;
  u16* dst = (seg == 0) ? Qb : (seg == 1) ? Kb : Vb;
  const float scl = (seg == 0) ? SCL_LOG2E : 1.0f;
#pragma unroll
  for (int j = 0; j < 4; ++j) {
    const int nn = (n0 & 1023) + wc * 64 + j * 16 + l16;
    const float bvs = bias[nn];
    const int h = nn >> 6, dh = nn & 63;
#pragma unroll
    for (int i = 0; i < 4; ++i) {
      const int rb = m0 + wr * 64 + i * 16 + quad * 4;
#pragma unroll
      for (int r = 0; r < 4; ++r) {
        const int m = rb + r;
        const int b = m >> 11, ll = m & 2047;
        dst[((size_t)(b * 16 + h) * 2048 + ll) * 64 + dh] = f2bf((acc[i][j][r] + bvs) * scl);
      }
    }
  }
}

// ---------------------------------------------------------------------------
// Out GEMM: C[M,N] f32 = A[M,K] bf16 @ Bt[N,K]^T + bias[N]. M=8192 N=K=1024.
// XCD-chunked block swizzle: 64 blocks (8 m-panels x 8) per XCD.
__global__ __launch_bounds__(256, 2) void gemm_out(
    const u16* __restrict__ A, const u16* __restrict__ Bt,
    const float* __restrict__ bias, float* __restrict__ C, int M, int N, int K) {
  __shared__ __align__(16) u16 As[128 * 32];
  __shared__ __align__(16) u16 Bs[128 * 32];
  const int t = threadIdx.x;
  const int w = t >> 6, l = t & 63;
  const int quad = l >> 4, l16 = l & 15;
  const int lin = blockIdx.y * 8 + blockIdx.x;   // 0..511
  const int nl = (lin & 7) * 64 + (lin >> 3);    // XCD-chunked remap
  const int m0 = (nl >> 3) * 128, n0 = (nl & 7) * 128;
  const int wr = w >> 1, wc = w & 1;

  floatx4 acc[4][4] = {};

  for (int k0 = 0; k0 < K; k0 += 32) {
    __syncthreads();
#pragma unroll
    for (int p = 0; p < 2; ++p) {
      const int c0 = (p * 4 + w) * 64;
      const int c = c0 + l;
      const int row = c >> 2;
      const int koff = (c & 3) * 8;
      gll16(A + (size_t)(m0 + row) * K + k0 + koff, &As[c0 * 8]);
      gll16(Bt + (size_t)(n0 + row) * K + k0 + koff, &Bs[c0 * 8]);
    }
    __syncthreads();

    short8 af[4], bf[4];
#pragma unroll
    for (int i = 0; i < 4; ++i)
      af[i] = *(const short8*)&As[(wr * 64 + i * 16 + l16) * 32 + quad * 8];
#pragma unroll
    for (int j = 0; j < 4; ++j)
      bf[j] = *(const short8*)&Bs[(wc * 64 + j * 16 + l16) * 32 + quad * 8];
#pragma unroll
    for (int i = 0; i < 4; ++i)
#pragma unroll
      for (int j = 0; j < 4; ++j)
        acc[i][j] = __builtin_amdgcn_mfma_f32_16x16x32_bf16(af[i], bf[j], acc[i][j], 0, 0, 0);
  }

#pragma unroll
  for (int j = 0; j < 4; ++j) {
    const int n = n0 + wc * 64 + j * 16 + l16;
    const float bvs = bias[n];
#pragma unroll
    for (int i = 0; i < 4; ++i) {
      const int rb = m0 + wr * 64 + i * 16 + quad * 4;
#pragma unroll
      for (int r = 0; r < 4; ++r)
        C[(size_t)(rb + r) * N + n] = acc[i][j][r] + bvs;
    }
  }
}

// ---------------------------------------------------------------------------
// Flash attention, causal. 512-thread blocks (8 waves x 16 q-rows = q-tile
// 128) sharing 64x64 K/V tiles double-buffered via gll16 with chunk-XOR
// swizzle. Block = q-tile pair (15-pp, pp) -> exactly 34 k-iters per block;
// grid 8x64 = 512 blocks = 2/CU (LDS 48KB). XCD remap: 8 bh per XCD L2.
// ONE __syncthreads per k-tile.
//
// Swapped-operand MFMA: s = mfma(K_frag, Q_frag) -> S^T: lane(quad,l16) holds
// S[k = kt*64 + tn*16+quad*4+r][q = l16]. Softmax: v_max3 tree + 2 shfl_xor,
// exp2 domain (Q pre-scaled), defer-max THR=8. lsum via MFMA ones-column:
// lacc = mfma(ones, ap[ks], lacc) -> every lane holds the full column sum
// (no VALU adds, no shuffles). P -> bf16 pairs via v_cvt_pk_bf16_f32 ->
// wave-private swizzled LDS (4x ds_write_b64) -> 2x ds_read_b128 -> PV.
__global__ __launch_bounds__(512, 4) void attn_kernel(
    const u16* __restrict__ Q, const u16* __restrict__ K,
    const u16* __restrict__ Vt, u16* __restrict__ ctx) {
  __shared__ __align__(16) u16 Ks[2][64 * 64];
  __shared__ __align__(16) u16 Vs[2][64 * 64];
  __shared__ __align__(16) u16 Ps[8 * 16 * 64];

  const int t = threadIdx.x;
  const int w = t >> 6, l = t & 63;
  const int quad = l >> 4, l16 = l & 15;
  // XCD remap: consecutive HW block ids round-robin XCDs; each XCD gets 8
  // consecutive bh (4MB K+V = one L2) across all pair indices.
  const int lin = blockIdx.y * 8 + blockIdx.x;  // gridDim.x == 8
  const int bh = (lin & 7) * 8 + ((lin >> 3) & 7);
  const int pp = lin >> 6;  // 0..7
  const size_t base = (size_t)bh * (2048 * 64);
  const int b = bh >> 4, h = bh & 15;
  u16* Pw = &Ps[w * 16 * 64];
  unsigned int* Pw32 = (unsigned int*)Pw;

  const short8 vone = {(short)0x3F80, (short)0x3F80, (short)0x3F80, (short)0x3F80,
                       (short)0x3F80, (short)0x3F80, (short)0x3F80, (short)0x3F80};

  // staging geometry: phys chunk pc = w*64 + l; logical row sr = pc>>3,
  // chunk sc = (pc&7) ^ (sr&7). gll16 dest = chunk-contiguous (lane*16).
  const int pc = w * 64 + l;
  const int sr = pc >> 3, sc = (pc & 7) ^ (sr & 7);
  const int swz = (l16 & 7);  // fragment-read chunk swizzle

  auto run_seg = [&](int p) {
    const int q0 = p * 128;
    const int nkt = 2 * p + 2;           // causal k-tiles of 64
    const int qg = q0 + w * 16 + l16;    // this lane's q row
    const int qmax = q0 + w * 16 + 15;   // wave's max q
    const int qmin = q0 + w * 16;        // wave's min q

    // Q fragments (lane's l16 = q-row): k = ks*32+quad*8
    short8 aq[2];
#pragma unroll
    for (int ks = 0; ks < 2; ++ks)
      aq[ks] = *(const short8*)(Q + base + (size_t)qg * 64 + ks * 32 + quad * 8);

    // prefetch tile 0 into buf 0 (1 K-chunk + 1 V-chunk per wave)
    gll16(K + base + (size_t)sr * 64 + sc * 8, &Ks[0][(w * 64) * 8]);
    gll16(Vt + base + (size_t)sr * 2048 + sc * 8, &Vs[0][(w * 64) * 8]);

    floatx4 o[4] = {};
    floatx4 lacc = {};
    float mrun = NEG_BIG;

    for (int kt = 0; kt < nkt; ++kt) {
      const int cur = kt & 1, nxt = cur ^ 1;
      __syncthreads();  // drains gll16s for buf[cur]; protects buf[nxt]
      if (kt + 1 < nkt) {
        const int kn = (kt + 1) * 64;
        gll16(K + base + (size_t)(kn + sr) * 64 + sc * 8, &Ks[nxt][(w * 64) * 8]);
        gll16(Vt + base + (size_t)sr * 2048 + kn + sc * 8, &Vs[nxt][(w * 64) * 8]);
      }
      const int kbase = kt * 64;
      if (kbase > qmax) continue;  // fully-masked wave: barrier+staging only
      const bool masked = (kbase + 63 > qmin);  // wave-uniform

      // S^T = K Q^T : 8 MFMA (swapped operands); K frag row tn*16+l16
      floatx4 s[4] = {};
      __builtin_amdgcn_s_setprio(1);
#pragma unroll
      for (int ks = 0; ks < 2; ++ks)
#pragma unroll
        for (int tn = 0; tn < 4; ++tn) {
          const short8 bk = *(const short8*)&Ks[cur][(tn * 16 + l16) * 64 + (((ks * 4 + quad) ^ swz) << 3)];
          s[tn] = __builtin_amdgcn_mfma_f32_16x16x32_bf16(bk, aq[ks], s[tn], 0, 0, 0);
        }
      __builtin_amdgcn_s_setprio(0);

      // causal mask (diag-crossing tiles only; Q pre-scaled, log2 domain)
      if (masked) {
#pragma unroll
        for (int tn = 0; tn < 4; ++tn)
#pragma unroll
          for (int r = 0; r < 4; ++r)
            if (kbase + tn * 16 + quad * 4 + r > qg) s[tn][r] = NEG_BIG;
      }
      // in-lane 16-value max: v_max3 tree (8 instrs)
      const float m0t = max3f(s[0][0], s[0][1], s[0][2]);
      const float m1t = max3f(s[0][3], s[1][0], s[1][1]);
      const float m2t = max3f(s[1][2], s[1][3], s[2][0]);
      const float m3t = max3f(s[2][1], s[2][2], s[2][3]);
      const float m4t = max3f(s[3][0], s[3][1], s[3][2]);
      float mx = fmaxf(max3f(m0t, m1t, m2t), max3f(m3t, m4t, s[3][3]));
      // cross-quad (same q lives in lanes l16, l16+16, l16+32, l16+48)
      mx = fmaxf(mx, __shfl_xor(mx, 16));
      mx = fmaxf(mx, __shfl_xor(mx, 32));

      // defer-max: rescale only when the max grows by more than THR=8.
      if (!__all(mx - mrun <= 8.f)) {
        const float mnew = fmaxf(mrun, mx);
        const float al = exp2f(mrun - mnew);
        mrun = mnew;
#pragma unroll
        for (int r = 0; r < 4; ++r) lacc[r] *= al;
#pragma unroll
        for (int td = 0; td < 4; ++td)
#pragma unroll
          for (int r = 0; r < 4; ++r) o[td][r] *= al;
      }

#pragma unroll
      for (int tn = 0; tn < 4; ++tn)
#pragma unroll
        for (int r = 0; r < 4; ++r)
          s[tn][r] = exp2f(s[tn][r] - mrun);

      // P: pack k-pairs -> 2x u32 per tn, one ds_write_b64 each.
      // u32 word k2 = 8*tn + 2*quad + p; chunk c = 2*tn + (quad>>1);
      // swizzled chunk cc = c ^ swz; intra-chunk offset 2*(quad&1)+p.
#pragma unroll
      for (int tn = 0; tn < 4; ++tn) {
        unsigned int p0, p1;
        asm("v_cvt_pk_bf16_f32 %0, %1, %2"
            : "=v"(p0) : "v"(s[tn][0]), "v"(s[tn][1]));
        asm("v_cvt_pk_bf16_f32 %0, %1, %2"
            : "=v"(p1) : "v"(s[tn][2]), "v"(s[tn][3]));
        const int cc = (2 * tn + (quad >> 1)) ^ swz;
        uint2v pr; pr.x = p0; pr.y = p1;
        *(uint2v*)&Pw32[l16 * 32 + cc * 4 + 2 * (quad & 1)] = pr;
      }
      __asm__ volatile("s_waitcnt lgkmcnt(0)" ::: "memory");
      __builtin_amdgcn_wave_barrier();

      // P fragment (B-operand): row l16 = q, k = ks*32+quad*8..+7 (de-swz)
      short8 ap[2];
#pragma unroll
      for (int ks = 0; ks < 2; ++ks)
        ap[ks] = *(const short8*)&Pw[l16 * 64 + (((ks * 4 + quad) ^ swz) << 3)];

      // O^T += V^T P^T : 8 MFMA (swapped); Vt frag row td*16+l16 (=dh).
      // lsum via ones-column: lacc[i][q] += sum_k P[k][q] (all i equal).
      __builtin_amdgcn_s_setprio(1);
      lacc = __builtin_amdgcn_mfma_f32_16x16x32_bf16(vone, ap[0], lacc, 0, 0, 0);
      lacc = __builtin_amdgcn_mfma_f32_16x16x32_bf16(vone, ap[1], lacc, 0, 0, 0);
#pragma unroll
      for (int ks = 0; ks < 2; ++ks)
#pragma unroll
        for (int td = 0; td < 4; ++td) {
          const short8 bv = *(const short8*)&Vs[cur][(td * 16 + l16) * 64 + (((ks * 4 + quad) ^ swz) << 3)];
          o[td] = __builtin_amdgcn_mfma_f32_16x16x32_bf16(bv, ap[ks], o[td], 0, 0, 0);
        }
      __builtin_amdgcn_s_setprio(0);
    }

    // normalize + store ctx[b, qg, h*64 + d]; lane q = l16, d = td*16+quad*4+r
    const float inv = 1.f / lacc[0];
    u16* crow = ctx + ((size_t)(b * 2048 + qg)) * 1024 + h * 64;
#pragma unroll
    for (int td = 0; td < 4; ++td) {
      unsigned int lo, hi;
      asm("v_cvt_pk_bf16_f32 %0, %1, %2"
          : "=v"(lo) : "v"(o[td][0] * inv), "v"(o[td][1] * inv));
      asm("v_cvt_pk_bf16_f32 %0, %1, %2"
          : "=v"(hi) : "v"(o[td][2] * inv), "v"(o[td][3] * inv));
      uint2v pk;
      pk.x = lo; pk.y = hi;
      *(uint2v*)(crow + td * 16 + quad * 4) = pk;
    }
  };

  run_seg(15 - pp);   // heavy segment: nkt in [18,32]
  __syncthreads();    // protect buffers before re-prefetch
  run_seg(pp);        // light segment: nkt in [2,16]
}

// ---------------------------------------------------------------------------
extern "C" void kernel_launch(void* const* d_in, const int* in_sizes, int n_in,
                              void* d_out, int out_size, void* d_ws, size_t ws_size,
                              hipStream_t stream) {
  const float* x  = (const float*)d_in[0];
  // d_in[1] = attn_mask (causal tril) — implemented analytically
  const float* Wq = (const float*)d_in[2];
  const float* bq = (const float*)d_in[3];
  const float* Wk = (const float*)d_in[4];
  const float* bk = (const float*)d_in[5];
  const float* Wv = (const float*)d_in[6];
  const float* bv = (const float*)d_in[7];
  const float* Wo = (const float*)d_in[8];
  const float* bo = (const float*)d_in[9];

  u16* ws = (u16*)d_ws;
  const size_t WSZ = 1u << 20;   // 1024*1024
  const size_t TSZ = 8u << 20;   // 8192*1024
  u16* WqT = ws;                 // WqT|WkT|WvT contiguous = 3072x1024 Bt
  u16* WkT = ws + WSZ;
  u16* WvT = ws + 2 * WSZ;
  u16* WoT = ws + 3 * WSZ;
  u16* xb  = ws + 4 * WSZ;       // x bf16; dead after gemm_qkv -> reused as Vtb
  u16* Qb  = xb + TSZ;
  u16* Kb  = Qb + TSZ;
  u16* Vb  = Kb + TSZ;           // V [b,h,l,dh]; dead after transpose_v -> Ctx
  u16* Vtb = xb;
  u16* Ctx = Vb;

  const dim3 tb(256);
  cvt_x<<<dim3(4096), tb, 0, stream>>>(x, xb);
  transpose4<<<dim3(16, 16, 4), tb, 0, stream>>>(Wq, Wk, Wv, Wo, WqT, WkT, WvT, WoT);
  gemm_qkv<<<dim3(24, 64), tb, 0, stream>>>(xb, WqT, bq, bk, bv, Qb, Kb, Vb);
  transpose_v<<<dim3(32, 64), tb, 0, stream>>>(Vb, Vtb);
  attn_kernel<<<dim3(8, 64), dim3(512), 0, stream>>>(Qb, Kb, Vtb, Ctx);
  gemm_out<<<dim3(8, 64), tb, 0, stream>>>(Ctx, WoT, bo, (float*)d_out, 8192, 1024, 1024);
}